// Round 4
// baseline (652.251 us; speedup 1.0000x reference)
//
#include <hip/hip_runtime.h>

#define N_    16
#define CIN_  64
#define HW_   56
#define COUT_ 64
#define HP    58            // padded H/W
#define HPSQ  (HP * HP)     // 3364

typedef float f4u __attribute__((ext_vector_type(4), aligned(4)));  // dword-aligned vec load

// ---- kernel 1: zero-padded copy of x into ws: xp[n][ci][58][58] ----
__global__ void pad_x_kernel(const float* __restrict__ x, float* __restrict__ xp) {
    int idx = blockIdx.x * 256 + threadIdx.x;
    const int total = N_ * CIN_ * HPSQ;
    if (idx >= total) return;
    int w  = idx % HP;
    int t  = idx / HP;
    int h  = t % HP;
    int nc = t / HP;
    float v = 0.f;
    if (h >= 1 && h <= HW_ && w >= 1 && w <= HW_)
        v = x[((size_t)nc * HW_ + (h - 1)) * HW_ + (w - 1)];
    xp[idx] = v;
}

// ---- kernel 2: main AdderNet kernel ----
// Grid: 1024 blocks = one per (n, co).  Block: 256 threads = 4 waves.
// Wave wid handles ci in [wid*16, wid*16+16); lane = 8x8 grid of 7x7 tiles.
// Ping-pong: full 9x9 rows of ci+1 load while ci computes (882 VALU = 1764cy
// of cover).  bufA+bufB+acc ~ 220 VGPR -> launch_bounds(256,2): 2 waves/SIMD,
// 1024 blocks = exactly 2 blocks/CU resident.  Round-3 lesson: at (256,4) the
// compiler shrank to 60 VGPR and re-issued loads per COMP (FETCH 4x xp).
__global__ __launch_bounds__(256, 2) void adder_main_kernel(
    const float* __restrict__ xp, const float* __restrict__ wt,
    float* __restrict__ out) {
    __shared__ float red[3][64][49];   // stride 49 (odd) -> conflict-free

    int bid  = blockIdx.x;
    int n    = bid >> 6;
    int co   = bid & 63;
    int tid  = threadIdx.x;
    int wid  = tid >> 6;            // wave id 0..3
    int lane = tid & 63;
    int tx   = lane & 7;
    int ty   = lane >> 3;
    int h0   = ty * 7;
    int w0   = tx * 7;

    const float* xbase = xp + (size_t)n * CIN_ * HPSQ + h0 * HP + w0;
    const float* wbase = wt + (size_t)co * 576;   // adder[co] contiguous (ci,kh,kw)

    float acc[7][7] = {};
    float bufA[9][9], bufB[9][9];

    #define LOADCI(buf, xc) { \
        _Pragma("unroll") \
        for (int r = 0; r < 9; ++r) { \
            f4u a_ = *(const f4u*)((xc) + r * HP);      \
            f4u b_ = *(const f4u*)((xc) + r * HP + 4);  \
            buf[r][0] = a_.x; buf[r][1] = a_.y; buf[r][2] = a_.z; buf[r][3] = a_.w; \
            buf[r][4] = b_.x; buf[r][5] = b_.y; buf[r][6] = b_.z; buf[r][7] = b_.w; \
            buf[r][8] = (xc)[r * HP + 8]; } }

    #define COMPCI(buf, wci) { \
        float w9[9]; \
        _Pragma("unroll") \
        for (int k = 0; k < 9; ++k) w9[k] = (wci)[k]; \
        _Pragma("unroll") \
        for (int oh = 0; oh < 7; ++oh) \
            _Pragma("unroll") \
            for (int kh = 0; kh < 3; ++kh) \
                _Pragma("unroll") \
                for (int kw = 0; kw < 3; ++kw) { \
                    float wv = w9[kh * 3 + kw]; \
                    _Pragma("unroll") \
                    for (int j = 0; j < 7; ++j) \
                        acc[oh][j] += fabsf(buf[oh + kh][j + kw] - wv); \
                } }

    const int ci0 = wid * 16;
    LOADCI(bufA, xbase + (size_t)ci0 * HPSQ)           // prologue
    for (int i = 0; i < 8; ++i) {
        int ci = ci0 + 2 * i;
        // load next while computing current (ping-pong)
        LOADCI(bufB, xbase + (size_t)(ci + 1) * HPSQ)
        COMPCI(bufA, wbase + ci * 9)
        int pci = (i < 7) ? (ci + 2) : ci0;            // clamp: avoid OOB prefetch
        LOADCI(bufA, xbase + (size_t)pci * HPSQ)
        COMPCI(bufB, wbase + (ci + 1) * 9)
    }
    #undef LOADCI
    #undef COMPCI

    if (wid != 0) {
        float* rp = &red[wid - 1][lane][0];
        #pragma unroll
        for (int oh = 0; oh < 7; ++oh)
            #pragma unroll
            for (int j = 0; j < 7; ++j) rp[oh * 7 + j] = acc[oh][j];
    }
    __syncthreads();
    if (wid == 0) {
        float* ob = out + (((size_t)(n * COUT_ + co)) * HW_ + h0) * HW_ + w0;
        #pragma unroll
        for (int oh = 0; oh < 7; ++oh)
            #pragma unroll
            for (int j = 0; j < 7; ++j) {
                float s = acc[oh][j]
                        + red[0][lane][oh * 7 + j]
                        + red[1][lane][oh * 7 + j]
                        + red[2][lane][oh * 7 + j];
                ob[oh * HW_ + j] = -s;
            }
    }
}

extern "C" void kernel_launch(void* const* d_in, const int* in_sizes, int n_in,
                              void* d_out, int out_size, void* d_ws, size_t ws_size,
                              hipStream_t stream) {
    const float* x     = (const float*)d_in[0];
    const float* adder = (const float*)d_in[1];
    float* out = (float*)d_out;

    float* xp = (float*)d_ws;   // 16*64*58*58*4 = 13.78 MB of ws

    const int padTotal = N_ * CIN_ * HPSQ;
    pad_x_kernel<<<(padTotal + 255) / 256, 256, 0, stream>>>(x, xp);
    adder_main_kernel<<<N_ * COUT_, 256, 0, stream>>>(xp, adder, out);
}

// Round 5
// 200.066 us; speedup vs baseline: 3.2602x; 3.2602x over previous
//
#include <hip/hip_runtime.h>

#define N_    16
#define CIN_  64
#define HW_   56
#define COUT_ 64
#define HPR   58                 // padded rows
#define WST   60                 // padded row stride (dwords, mult of 4)
#define PLANE (HPR * WST)        // 3480 dwords used
#define PLANE_PAD 3584           // 14 chunks of 256 dwords (64 lanes x 16B)

// ---- kernel 1: zero-padded copy of x into ws: xp[n][ci][3584] ----
// Row stride 60, plane stride 3584 so global_load_lds (linear, 16B/lane)
// stages a plane as an identity copy with no tail handling.
__global__ void pad_x_kernel(const float* __restrict__ x, float* __restrict__ xp) {
    int idx = blockIdx.x * 256 + threadIdx.x;
    const int total = N_ * CIN_ * PLANE_PAD;
    if (idx >= total) return;
    int rem = idx % PLANE_PAD;
    int nc  = idx / PLANE_PAD;
    int h   = rem / WST;
    int w   = rem % WST;
    float v = 0.f;
    if (h >= 1 && h <= HW_ && w >= 1 && w <= HW_)
        v = x[((size_t)nc * HW_ + (h - 1)) * HW_ + (w - 1)];
    xp[idx] = v;
}

// ---- kernel 2: main AdderNet kernel ----
// Block 256 thr = 4 waves: wave = (coidx = wid>>1, cihalf = wid&1).
// Grid 16n x 32 co-pairs = 512 blocks = 2/CU -> 2 waves/SIMD (2048 waves).
// Per iter: each wave computes one ci plane (882 VALU) from LDS buf[cur];
// global_load_lds stages the next 2 planes into buf[cur^1]; 1 barrier/iter.
// R3/R4 lesson: reg-resident prefetch gets sunk (R3) or spilled (R4) by the
// compiler; LDS + barrier staging is structurally immune to both.
__global__ __launch_bounds__(256, 2) void adder_main_kernel(
    const float* __restrict__ xp, const float* __restrict__ wt,
    float* __restrict__ out) {
    __shared__ float lds[2][2][PLANE_PAD];   // [dbuf][cihalf][plane] = 57,344 B

    const int bid  = blockIdx.x;
    const int n    = bid >> 5;
    const int cop  = bid & 31;
    const int tid  = threadIdx.x;
    const int wid  = tid >> 6;
    const int lane = tid & 63;
    const int coidx  = wid >> 1;          // which co of the pair
    const int cihalf = wid & 1;           // 0: ci 0..31, 1: ci 32..63
    const int co   = cop * 2 + coidx;
    const int tx = lane & 7, ty = lane >> 3;
    const int h0 = ty * 7, w0 = tx * 7;

    const int sgH = wid >> 1;             // staging: waves 0,1 -> half0; 2,3 -> half1
    const int sgW = wid & 1;              // chunk parity within staging pair
    const size_t gplane0 = (size_t)(n * CIN_) * PLANE_PAD;

    // 7 chunks/wave x 64 lanes x 16B: two waves cover one 14-chunk plane.
    #define STAGEP(bufi, ci_) { \
        const float* gsrc_ = xp + gplane0 + (size_t)(sgH * 32 + (ci_)) * PLANE_PAD; \
        float* ldst_ = &lds[bufi][sgH][0]; \
        _Pragma("unroll") \
        for (int k_ = 0; k_ < 7; ++k_) { \
            int ch_ = k_ * 2 + sgW; \
            __builtin_amdgcn_global_load_lds( \
                (const __attribute__((address_space(1))) void*)(gsrc_ + ch_ * 256 + lane * 4), \
                (__attribute__((address_space(3))) void*)(ldst_ + ch_ * 256), 16, 0, 0); \
        } }

    float acc[7][7] = {};
    const int rb = h0 * WST + w0;

    STAGEP(0, 0)                 // prologue: stage ci_=0 planes into buf 0
    __syncthreads();             // (compiler drains vmcnt before s_barrier)

    for (int it = 0; it < 32; ++it) {
        const int cur = it & 1;
        if (it < 31) STAGEP(cur ^ 1, it + 1)   // async: lands during compute

        const float* lp = &lds[cur][cihalf][0];
        const int ci = cihalf * 32 + it;
        const float* wp = wt + (size_t)co * 576 + (size_t)ci * 9;
        float w9[9];
        #pragma unroll
        for (int k = 0; k < 9; ++k) w9[k] = wp[k];   // wave-uniform -> s_load

        float buf[9][9];   // rolling liveness <= 5 rows (static indices only)
        #define LROW(r) { _Pragma("unroll") \
            for (int c = 0; c < 9; ++c) buf[r][c] = lp[rb + (r) * WST + c]; }
        #define CROW(oh) { _Pragma("unroll") \
            for (int kh = 0; kh < 3; ++kh) { \
                _Pragma("unroll") \
                for (int kw = 0; kw < 3; ++kw) { \
                    float wv = w9[kh * 3 + kw]; \
                    _Pragma("unroll") \
                    for (int j = 0; j < 7; ++j) \
                        acc[oh][j] += fabsf(buf[(oh) + kh][j + kw] - wv); \
                } } }

        LROW(0) LROW(1) LROW(2) LROW(3)   // 2-row lookahead vs first use
        CROW(0) LROW(4)
        CROW(1) LROW(5)
        CROW(2) LROW(6)
        CROW(3) LROW(7)
        CROW(4) LROW(8)
        CROW(5)
        CROW(6)
        #undef LROW
        #undef CROW

        __syncthreads();   // buf[cur^1] staged complete; buf[cur] reads done
    }

    // reduce ci-halves: wave(cihalf=1) -> LDS, wave(cihalf=0) adds + stores.
    float* red = &lds[0][0][0];            // reuse staging LDS (6272 floats)
    if (cihalf == 1) {
        float* rp = red + (size_t)(coidx * 64 + lane) * 49;   // stride 49: conflict-free
        #pragma unroll
        for (int oh = 0; oh < 7; ++oh)
            #pragma unroll
            for (int j = 0; j < 7; ++j) rp[oh * 7 + j] = acc[oh][j];
    }
    __syncthreads();
    if (cihalf == 0) {
        const float* rp = red + (size_t)(coidx * 64 + lane) * 49;
        float* ob = out + (((size_t)(n * COUT_ + co)) * HW_ + h0) * HW_ + w0;
        #pragma unroll
        for (int oh = 0; oh < 7; ++oh)
            #pragma unroll
            for (int j = 0; j < 7; ++j)
                ob[oh * HW_ + j] = -(acc[oh][j] + rp[oh * 7 + j]);
    }
    #undef STAGEP
}

extern "C" void kernel_launch(void* const* d_in, const int* in_sizes, int n_in,
                              void* d_out, int out_size, void* d_ws, size_t ws_size,
                              hipStream_t stream) {
    const float* x     = (const float*)d_in[0];
    const float* adder = (const float*)d_in[1];
    float* out = (float*)d_out;

    float* xp = (float*)d_ws;   // 16*64*3584*4 = 14.68 MB of ws

    const int padTotal = N_ * CIN_ * PLANE_PAD;
    pad_x_kernel<<<(padTotal + 255) / 256, 256, 0, stream>>>(x, xp);
    adder_main_kernel<<<N_ * 32, 256, 0, stream>>>(xp, adder, out);
}